// Round 17
// baseline (213.125 us; speedup 1.0000x reference)
//
#include <hip/hip_runtime.h>

// GCN 2-layer: N=100000, E=3200000, IN=8, HID=64, OUT=1.
// Round 17: R16 pipeline + (1) int4/float4-vectorized A-phase loads,
// (2) scan1+scan2B fused via last-block-done (counter zeroed by kA_hist,
// device-scope atomic + threadfence), (3) scatter2's lh from registers +
// int4 gO/gP. Proven parts untouched: run-coalesced scatter (R12),
// register-parked single-pass sortdeg (R16), 8-thr/node kB2/kB3 (R15).

#define N_    100000
#define E_    3200000
#define BK    2048        // buckets = col >> 6 (64 nodes/bucket)
#define NBUCK 1563        // ceil(N_/64)
#define CA    500         // chunks (= scatter blocks)
#define CSA   6400        // E_/CA
#define GG    10          // chunk groups
#define GCH   50          // chunks per group
#define SCE   6400        // edges per scatter block
#define NSCAN 20          // fused-scan blocks (20 x 1024 = GG*BK threads)

// ---- A1: per-(chunk,bucket) histogram, int4 loads. Also zeroes sync ctr.
__global__ __launch_bounds__(512)
void kA_hist(const int* __restrict__ col, int* __restrict__ countsA,
             int* __restrict__ syncc) {
    __shared__ int bins[BK];
    int c = blockIdx.x, t = threadIdx.x;
    if (c == 0 && t == 0) syncc[0] = 0;
    ((int4*)bins)[t] = make_int4(0, 0, 0, 0);
    __syncthreads();
    const int4* cp4 = (const int4*)(col + c * CSA);   // 1600 int4
    #pragma unroll
    for (int it = 0; it < 3; it++) {
        int4 v = cp4[t + it * 512];
        atomicAdd(&bins[v.x >> 6], 1);
        atomicAdd(&bins[v.y >> 6], 1);
        atomicAdd(&bins[v.z >> 6], 1);
        atomicAdd(&bins[v.w >> 6], 1);
    }
    if (t < 64) {
        int4 v = cp4[1536 + t];
        atomicAdd(&bins[v.x >> 6], 1);
        atomicAdd(&bins[v.y >> 6], 1);
        atomicAdd(&bins[v.z >> 6], 1);
        atomicAdd(&bins[v.w >> 6], 1);
    }
    __syncthreads();
    ((int4*)(countsA + (size_t)c * BK))[t] = ((int4*)bins)[t];
}

// ---- A2 fused: within-group prefix (all blocks) + cross-group/bucket scan
//      + fold (last block only, via device-scope counter).
__global__ __launch_bounds__(1024)
void kA_scanF(const int* __restrict__ countsA, int* __restrict__ countsP,
              int* __restrict__ grptot, int* __restrict__ baseB,
              int* __restrict__ syncc) {
    int t = threadIdx.x;
    int tid = blockIdx.x * 1024 + t;        // NSCAN*1024 = GG*BK
    int g = tid >> 11;
    int b = tid & (BK - 1);
    int c0 = g * GCH;
    int run = 0;
    #pragma unroll 5
    for (int k = 0; k < GCH; k++) {
        size_t idx = (size_t)(c0 + k) * BK + b;
        int v = countsA[idx];
        countsP[idx] = run;
        run += v;
    }
    grptot[g * BK + b] = run;
    __threadfence();
    __syncthreads();
    __shared__ int lastdone;
    if (t == 0) lastdone = (atomicAdd(&syncc[0], 1) == NSCAN - 1) ? 1 : 0;
    __syncthreads();
    if (!lastdone) return;
    __threadfence();                        // acquire other blocks' grptot
    // ---- scan2B body (1024 threads) ----
    __shared__ int wsum[16];
    int tot0, tot1;
    {
        int bb = 2 * t, r2 = 0;
        #pragma unroll
        for (int gg = 0; gg < GG; gg++) {
            int idx = gg * BK + bb;
            int v = grptot[idx];
            grptot[idx] = r2;
            r2 += v;
        }
        tot0 = r2;
    }
    {
        int bb = 2 * t + 1, r2 = 0;
        #pragma unroll
        for (int gg = 0; gg < GG; gg++) {
            int idx = gg * BK + bb;
            int v = grptot[idx];
            grptot[idx] = r2;
            r2 += v;
        }
        tot1 = r2;
    }
    int pair = tot0 + tot1;
    int lane = t & 63, wv = t >> 6;
    int val = pair;
    #pragma unroll
    for (int d = 1; d < 64; d <<= 1) {
        int u = __shfl_up(val, d);
        if (lane >= d) val += u;
    }
    if (lane == 63) wsum[wv] = val;
    __syncthreads();
    if (t == 0) {
        int r2 = 0;
        #pragma unroll
        for (int g2 = 0; g2 < 16; g2++) { int v = wsum[g2]; wsum[g2] = r2; r2 += v; }
    }
    __syncthreads();
    int excl = val - pair + wsum[wv];
    baseB[2 * t]     = excl;
    baseB[2 * t + 1] = excl + tot0;
    if (t == 1023) baseB[BK] = wsum[15] + __shfl(val, 63);   // == E_
    #pragma unroll
    for (int gg = 0; gg < GG; gg++) {
        grptot[gg * BK + 2 * t]     += excl;
        grptot[gg * BK + 2 * t + 1] += excl + tot0;
    }
}

// ---- A3: LDS bucket-sort 6400 edges, run-contiguous global writes.
__global__ __launch_bounds__(512)
void kA_scatter2(const int* __restrict__ row, const int* __restrict__ col,
                 const float* __restrict__ w,
                 const int* __restrict__ countsA, const int* __restrict__ countsP,
                 const int* __restrict__ grptot,
                 int2* __restrict__ brec) {
    __shared__ int  lh[BK];                 // shift
    __shared__ int  lc_[BK];                // local base -> bump cursor
    __shared__ int  wsum[8];
    __shared__ int2 srec[SCE];              // 51200 B
    __shared__ unsigned short sbid[SCE];    // 12800 B
    int c = blockIdx.x, t = threadIdx.x;
    int g = c / GCH;
    int E0 = c * SCE;
    int4 hv = ((const int4*)(countsA + (size_t)c * BK))[t];
    int tot = hv.x + hv.y + hv.z + hv.w;
    int lane = t & 63, wv = t >> 6;
    int val = tot;
    #pragma unroll
    for (int d = 1; d < 64; d <<= 1) {
        int u = __shfl_up(val, d);
        if (lane >= d) val += u;
    }
    if (lane == 63) wsum[wv] = val;
    __syncthreads();
    if (t == 0) {
        int r2 = 0;
        #pragma unroll
        for (int g2 = 0; g2 < 8; g2++) { int v = wsum[g2]; wsum[g2] = r2; r2 += v; }
    }
    __syncthreads();
    int excl = val - tot + wsum[wv];
    int l0 = excl, l1 = excl + hv.x, l2 = l1 + hv.y, l3 = l2 + hv.z;
    int b0 = t * 4;
    lc_[b0] = l0; lc_[b0 + 1] = l1; lc_[b0 + 2] = l2; lc_[b0 + 3] = l3;
    // lh from registers + int4 gO/gP (no LDS read-back)
    int4 go = ((const int4*)(grptot + g * BK))[t];
    int4 gp = ((const int4*)(countsP + (size_t)c * BK))[t];
    lh[b0]     = go.x + gp.x - l0;
    lh[b0 + 1] = go.y + gp.y - l1;
    lh[b0 + 2] = go.z + gp.z - l2;
    lh[b0 + 3] = go.w + gp.w - l3;
    __syncthreads();
    // staging pass: int4/float4 loads, 4 edges per iteration
    const int4*   cp4 = (const int4*)(col + E0);
    const int4*   rp4 = (const int4*)(row + E0);
    const float4* wp4 = (const float4*)(w + E0);
    #pragma unroll
    for (int it = 0; it < 3; it++) {
        int i4 = t + it * 512;
        int4 v = cp4[i4];
        int4 r = rp4[i4];
        float4 ww = wp4[i4];
        int bb, lp;
        bb = v.x >> 6; lp = atomicAdd(&lc_[bb], 1);
        srec[lp] = make_int2(r.x | ((v.x & 63) << 17), __float_as_int(ww.x));
        sbid[lp] = (unsigned short)bb;
        bb = v.y >> 6; lp = atomicAdd(&lc_[bb], 1);
        srec[lp] = make_int2(r.y | ((v.y & 63) << 17), __float_as_int(ww.y));
        sbid[lp] = (unsigned short)bb;
        bb = v.z >> 6; lp = atomicAdd(&lc_[bb], 1);
        srec[lp] = make_int2(r.z | ((v.z & 63) << 17), __float_as_int(ww.z));
        sbid[lp] = (unsigned short)bb;
        bb = v.w >> 6; lp = atomicAdd(&lc_[bb], 1);
        srec[lp] = make_int2(r.w | ((v.w & 63) << 17), __float_as_int(ww.w));
        sbid[lp] = (unsigned short)bb;
    }
    if (t < 64) {
        int i4 = 1536 + t;
        int4 v = cp4[i4];
        int4 r = rp4[i4];
        float4 ww = wp4[i4];
        int bb, lp;
        bb = v.x >> 6; lp = atomicAdd(&lc_[bb], 1);
        srec[lp] = make_int2(r.x | ((v.x & 63) << 17), __float_as_int(ww.x));
        sbid[lp] = (unsigned short)bb;
        bb = v.y >> 6; lp = atomicAdd(&lc_[bb], 1);
        srec[lp] = make_int2(r.y | ((v.y & 63) << 17), __float_as_int(ww.y));
        sbid[lp] = (unsigned short)bb;
        bb = v.z >> 6; lp = atomicAdd(&lc_[bb], 1);
        srec[lp] = make_int2(r.z | ((v.z & 63) << 17), __float_as_int(ww.z));
        sbid[lp] = (unsigned short)bb;
        bb = v.w >> 6; lp = atomicAdd(&lc_[bb], 1);
        srec[lp] = make_int2(r.w | ((v.w & 63) << 17), __float_as_int(ww.w));
        sbid[lp] = (unsigned short)bb;
    }
    __syncthreads();
    // run-contiguous write-out
    #pragma unroll 4
    for (int j = t; j < SCE; j += 512) {
        brec[lh[sbid[j]] + j] = srec[j];
    }
}

// ---- B-sort: per-bucket counting sort brec -> srt, single global pass.
__global__ __launch_bounds__(512)
void kB_sortdeg(const int* __restrict__ baseB, const int2* __restrict__ brec,
                int2* __restrict__ srt,
                const float* __restrict__ x,
                float* __restrict__ dinv, float* __restrict__ xw,
                int* __restrict__ nodeptr) {
    __shared__ int   h[8 * 64];
    __shared__ float degw[8 * 64];
    __shared__ int   nb[65];
    int b = blockIdx.x, t = threadIdx.x;
    int wid = t >> 6;
    int st = baseB[b];
    int cnt = baseB[b + 1] - st;
    h[t] = 0;
    degw[t] = 0.0f;
    __syncthreads();
    int hb = wid << 6;
    bool p0 = t < cnt, p1 = t + 512 < cnt, p2 = t + 1024 < cnt,
         p3 = t + 1536 < cnt, p4 = t + 2048 < cnt;
    int2 q0 = p0 ? brec[st + t]        : make_int2(0, 0);
    int2 q1 = p1 ? brec[st + t + 512]  : make_int2(0, 0);
    int2 q2 = p2 ? brec[st + t + 1024] : make_int2(0, 0);
    int2 q3 = p3 ? brec[st + t + 1536] : make_int2(0, 0);
    int2 q4 = p4 ? brec[st + t + 2048] : make_int2(0, 0);
    if (p0) { atomicAdd(&h[hb + (q0.x >> 17)], 1); atomicAdd(&degw[hb + (q0.x >> 17)], __int_as_float(q0.y)); }
    if (p1) { atomicAdd(&h[hb + (q1.x >> 17)], 1); atomicAdd(&degw[hb + (q1.x >> 17)], __int_as_float(q1.y)); }
    if (p2) { atomicAdd(&h[hb + (q2.x >> 17)], 1); atomicAdd(&degw[hb + (q2.x >> 17)], __int_as_float(q2.y)); }
    if (p3) { atomicAdd(&h[hb + (q3.x >> 17)], 1); atomicAdd(&degw[hb + (q3.x >> 17)], __int_as_float(q3.y)); }
    if (p4) { atomicAdd(&h[hb + (q4.x >> 17)], 1); atomicAdd(&degw[hb + (q4.x >> 17)], __int_as_float(q4.y)); }
    for (int i = t + 2560; i < cnt; i += 512) {   // statistically never
        int2 q = brec[st + i];
        atomicAdd(&h[hb + (q.x >> 17)], 1);
        atomicAdd(&degw[hb + (q.x >> 17)], __int_as_float(q.y));
    }
    __syncthreads();
    if (t < 64) {
        int off = 0;
        #pragma unroll
        for (int w2 = 0; w2 < 8; w2++) {
            int cc = h[(w2 << 6) + t];
            h[(w2 << 6) + t] = off;
            off += cc;
        }
        int val = off;
        #pragma unroll
        for (int d = 1; d < 64; d <<= 1) {
            int u = __shfl_up(val, d);
            if (t >= d) val += u;
        }
        nb[t] = val - off;
        if (t == 63) nb[64] = val;
    }
    __syncthreads();
    if (t < 64) {
        int e2 = nb[t];
        #pragma unroll
        for (int w2 = 0; w2 < 8; w2++) h[(w2 << 6) + t] += e2;
    }
    __syncthreads();
    if (p0) { int p = atomicAdd(&h[hb + (q0.x >> 17)], 1); srt[st + p] = make_int2(q0.x & 0x1FFFF, q0.y); }
    if (p1) { int p = atomicAdd(&h[hb + (q1.x >> 17)], 1); srt[st + p] = make_int2(q1.x & 0x1FFFF, q1.y); }
    if (p2) { int p = atomicAdd(&h[hb + (q2.x >> 17)], 1); srt[st + p] = make_int2(q2.x & 0x1FFFF, q2.y); }
    if (p3) { int p = atomicAdd(&h[hb + (q3.x >> 17)], 1); srt[st + p] = make_int2(q3.x & 0x1FFFF, q3.y); }
    if (p4) { int p = atomicAdd(&h[hb + (q4.x >> 17)], 1); srt[st + p] = make_int2(q4.x & 0x1FFFF, q4.y); }
    for (int i = t + 2560; i < cnt; i += 512) {
        int2 q = brec[st + i];
        int pos = atomicAdd(&h[hb + (q.x >> 17)], 1);
        srt[st + pos] = make_int2(q.x & 0x1FFFF, q.y);
    }
    if (t < 64) {
        int n = (b << 6) + t;
        if (n < N_) {
            float d = degw[t]       + degw[64 + t]  + degw[128 + t] + degw[192 + t]
                    + degw[256 + t] + degw[320 + t] + degw[384 + t] + degw[448 + t];
            float di = rsqrtf(d + 1.0f);
            dinv[n] = di;
            nodeptr[n] = st + nb[t];
            const float4* xi = (const float4*)(x + (size_t)n * 8);
            float4 xa = xi[0], xb = xi[1];
            float4* o = (float4*)(xw + (size_t)n * 8);
            o[0] = make_float4(di * xa.x, di * xa.y, di * xa.z, di * xa.w);
            o[1] = make_float4(di * xb.x, di * xb.y, di * xb.z, di * xb.w);
        }
        if (b == NBUCK - 1 && t == 0) nodeptr[N_] = E_;
    }
}

// ---- B2: 8 threads/node register aggregation + split MLP. Zero atomics.
__global__ __launch_bounds__(512)
void kB2_node(const int* __restrict__ nodeptr, const int2* __restrict__ srec,
              const float* __restrict__ dinv,
              const float* __restrict__ xw,
              const float* __restrict__ W1,
              const float* __restrict__ b1,
              const float* __restrict__ W2,
              float* __restrict__ tv) {
    __shared__ float sW1[8 * 64];
    __shared__ float sb1[64];
    __shared__ float sW2[64];
    int t = threadIdx.x;                  // 512 threads, 64 nodes/block
    sW1[t] = W1[t];
    if (t < 64) { sb1[t] = b1[t]; sW2[t] = W2[t]; }
    __syncthreads();
    int n = blockIdx.x * 64 + (t >> 3);
    int q = t & 7;
    if (n >= N_) return;
    int st = nodeptr[n], en = nodeptr[n + 1];
    const float4* xw4 = (const float4*)xw;
    float a[8];
    if (q == 0) {
        float4 s0 = xw4[2 * n], s1 = xw4[2 * n + 1];
        a[0] = s0.x; a[1] = s0.y; a[2] = s0.z; a[3] = s0.w;
        a[4] = s1.x; a[5] = s1.y; a[6] = s1.z; a[7] = s1.w;
    } else {
        #pragma unroll
        for (int k = 0; k < 8; k++) a[k] = 0.0f;
    }
    int e = st + q;
    for (; e + 8 < en; e += 16) {
        int2 q0 = srec[e], q1 = srec[e + 8];
        float4 f0a = xw4[2 * q0.x], f0b = xw4[2 * q0.x + 1];
        float4 f1a = xw4[2 * q1.x], f1b = xw4[2 * q1.x + 1];
        float w0 = __int_as_float(q0.y), w1 = __int_as_float(q1.y);
        a[0] = fmaf(w0, f0a.x, a[0]); a[1] = fmaf(w0, f0a.y, a[1]);
        a[2] = fmaf(w0, f0a.z, a[2]); a[3] = fmaf(w0, f0a.w, a[3]);
        a[4] = fmaf(w0, f0b.x, a[4]); a[5] = fmaf(w0, f0b.y, a[5]);
        a[6] = fmaf(w0, f0b.z, a[6]); a[7] = fmaf(w0, f0b.w, a[7]);
        a[0] = fmaf(w1, f1a.x, a[0]); a[1] = fmaf(w1, f1a.y, a[1]);
        a[2] = fmaf(w1, f1a.z, a[2]); a[3] = fmaf(w1, f1a.w, a[3]);
        a[4] = fmaf(w1, f1b.x, a[4]); a[5] = fmaf(w1, f1b.y, a[5]);
        a[6] = fmaf(w1, f1b.z, a[6]); a[7] = fmaf(w1, f1b.w, a[7]);
    }
    if (e < en) {
        int2 qq = srec[e];
        float4 fa = xw4[2 * qq.x], fb = xw4[2 * qq.x + 1];
        float w0 = __int_as_float(qq.y);
        a[0] = fmaf(w0, fa.x, a[0]); a[1] = fmaf(w0, fa.y, a[1]);
        a[2] = fmaf(w0, fa.z, a[2]); a[3] = fmaf(w0, fa.w, a[3]);
        a[4] = fmaf(w0, fb.x, a[4]); a[5] = fmaf(w0, fb.y, a[5]);
        a[6] = fmaf(w0, fb.z, a[6]); a[7] = fmaf(w0, fb.w, a[7]);
    }
    #pragma unroll
    for (int k = 0; k < 8; k++) {
        a[k] += __shfl_xor(a[k], 1);
        a[k] += __shfl_xor(a[k], 2);
        a[k] += __shfl_xor(a[k], 4);
    }
    float di = dinv[n];
    #pragma unroll
    for (int k = 0; k < 8; k++) a[k] *= di;
    float sv = 0.0f;
    int jb = q << 3;
    #pragma unroll
    for (int j = 0; j < 8; j++) {
        int jj = jb + j;
        float h = sb1[jj];
        #pragma unroll
        for (int k = 0; k < 8; k++) h = fmaf(a[k], sW1[k * 64 + jj], h);
        sv = fmaf(fmaxf(h, 0.0f), sW2[jj], sv);
    }
    sv += __shfl_xor(sv, 1);
    sv += __shfl_xor(sv, 2);
    sv += __shfl_xor(sv, 4);
    if (q == 0) tv[n] = di * sv;
}

// ---- B3: 8 threads/node layer-2.
__global__ __launch_bounds__(512)
void kB3_node(const int* __restrict__ nodeptr, const int2* __restrict__ srec,
              const float* __restrict__ dinv,
              const float* __restrict__ tv,
              const float* __restrict__ b2,
              float* __restrict__ out) {
    int t = threadIdx.x;                  // 512 threads, 64 nodes/block
    int n = blockIdx.x * 64 + (t >> 3);
    int q = t & 7;
    if (n >= N_) return;
    int st = nodeptr[n], en = nodeptr[n + 1];
    float acc = (q == 0) ? tv[n] : 0.0f;
    int e = st + q;
    for (; e + 8 < en; e += 16) {
        int2 q0 = srec[e], q1 = srec[e + 8];
        float t0 = tv[q0.x], t1 = tv[q1.x];
        acc = fmaf(__int_as_float(q0.y), t0, acc);
        acc = fmaf(__int_as_float(q1.y), t1, acc);
    }
    if (e < en) {
        int2 qq = srec[e];
        acc = fmaf(__int_as_float(qq.y), tv[qq.x], acc);
    }
    acc += __shfl_xor(acc, 1);
    acc += __shfl_xor(acc, 2);
    acc += __shfl_xor(acc, 4);
    if (q == 0) out[n] = b2[0] + dinv[n] * acc;
}

extern "C" void kernel_launch(void* const* d_in, const int* in_sizes, int n_in,
                              void* d_out, int out_size, void* d_ws, size_t ws_size,
                              hipStream_t stream) {
    const float* x  = (const float*)d_in[0];
    const int*   ei = (const int*)d_in[1];    // [2, E] int32
    const float* w  = (const float*)d_in[2];
    const float* W1 = (const float*)d_in[3];
    const float* b1 = (const float*)d_in[4];
    const float* W2 = (const float*)d_in[5];
    const float* b2 = (const float*)d_in[6];
    float* out = (float*)d_out;

    const int* row = ei;
    const int* col = ei + E_;

    // ws (ints): countsA[1024000] | countsP[1024000] | grptot[20480] |
    //   baseB[2049 pad 2560] | syncc[64] | nodeptr[100352] | dinv[N] |
    //   xw[8N] | tv[N] | brec[E] int2 | srt[E] int2        ~64 MB
    int*   wsI     = (int*)d_ws;
    int*   countsA = wsI;
    int*   countsP = wsI + (size_t)CA * BK;          // 1024000
    int*   grptot  = countsP + (size_t)CA * BK;      // +1024000
    int*   baseB   = grptot + GG * BK;               // +20480
    int*   syncc   = baseB + 2560;
    int*   nodeptr = syncc + 64;
    float* dinv    = (float*)(nodeptr + 100352);
    float* xw      = dinv + N_;
    float* tv      = xw + (size_t)8 * N_;
    int2*  brec    = (int2*)(tv + N_);
    int2*  srt     = brec + E_;

    kA_hist    <<<CA, 512, 0, stream>>>(col, countsA, syncc);
    kA_scanF   <<<NSCAN, 1024, 0, stream>>>(countsA, countsP, grptot, baseB, syncc);
    kA_scatter2<<<CA, 512, 0, stream>>>(row, col, w, countsA, countsP, grptot, brec);
    kB_sortdeg <<<NBUCK, 512, 0, stream>>>(baseB, brec, srt, x, dinv, xw, nodeptr);
    kB2_node   <<<NBUCK, 512, 0, stream>>>(nodeptr, srt, dinv, xw, W1, b1, W2, tv);
    kB3_node   <<<NBUCK, 512, 0, stream>>>(nodeptr, srt, dinv, tv, b2, out);
}

// Round 18
// 203.223 us; speedup vs baseline: 1.0487x; 1.0487x over previous
//
#include <hip/hip_runtime.h>

// GCN 2-layer: N=100000, E=3200000, IN=8, HID=64, OUT=1.
// Round 18: exact revert to R16 (201us, best verified). R17's three-way
// change (int4 A-loads, fused scan, register lh) regressed to 213us with
// no counter attribution; re-establishing the proven baseline.
// Pipeline: hist -> group scan -> bucket scan -> run-coalesced scatter (R12)
// -> register-parked single-pass sortdeg (R16) -> 8-thr/node kB2/kB3 (R15).

#define N_    100000
#define E_    3200000
#define BK    2048        // buckets = col >> 6 (64 nodes/bucket)
#define NBUCK 1563        // ceil(N_/64)
#define CA    500         // chunks (= scatter blocks)
#define CSA   6400        // E_/CA
#define GG    10          // chunk groups
#define GCH   50          // chunks per group
#define SCE   6400        // edges per scatter block

// ---- A1: per-(chunk,bucket) histogram. countsA chunk-major [c][b], RAW.
__global__ void kA_hist(const int* __restrict__ col, int* __restrict__ countsA) {
    __shared__ int bins[BK];
    int c = blockIdx.x, t = threadIdx.x;
    for (int i = t; i < BK; i += 512) bins[i] = 0;
    __syncthreads();
    const int* cp = col + c * CSA;
    #pragma unroll
    for (int it = 0; it < 3; it++) {            // 3 x 4 x 512 = 6144
        int e = t + it * 2048;
        int v0 = cp[e], v1 = cp[e + 512], v2 = cp[e + 1024], v3 = cp[e + 1536];
        atomicAdd(&bins[v0 >> 6], 1);
        atomicAdd(&bins[v1 >> 6], 1);
        atomicAdd(&bins[v2 >> 6], 1);
        atomicAdd(&bins[v3 >> 6], 1);
    }
    if (t < 256) atomicAdd(&bins[cp[6144 + t] >> 6], 1);
    __syncthreads();
    int* outp = countsA + (size_t)c * BK;
    for (int i = t; i < BK; i += 512) outp[i] = bins[i];
}

// ---- A2a: within-group exclusive prefix across chunks (raw in, prefix out).
__global__ void kA_scan1(const int* __restrict__ countsA, int* __restrict__ countsP,
                         int* __restrict__ grptot) {
    int tid = blockIdx.x * 256 + threadIdx.x;   // GG*BK = 20480 threads
    if (tid >= GG * BK) return;
    int g = tid >> 11;
    int b = tid & (BK - 1);
    int c0 = g * GCH;
    int run = 0;
    #pragma unroll 5
    for (int k = 0; k < GCH; k++) {
        size_t idx = (size_t)(c0 + k) * BK + b;
        int v = countsA[idx];
        countsP[idx] = run;
        run += v;
    }
    grptot[g * BK + b] = run;
}

// ---- A2b (one block): scan grptot across groups, bucket-base scan, fold.
__global__ void kA_scan2B(int* __restrict__ grptot, int* __restrict__ baseB) {
    __shared__ int wsum[16];
    int t = threadIdx.x;
    int tot0, tot1;
    {
        int b = 2 * t, run = 0;
        #pragma unroll
        for (int g = 0; g < GG; g++) {
            int idx = g * BK + b;
            int v = grptot[idx];
            grptot[idx] = run;
            run += v;
        }
        tot0 = run;
    }
    {
        int b = 2 * t + 1, run = 0;
        #pragma unroll
        for (int g = 0; g < GG; g++) {
            int idx = g * BK + b;
            int v = grptot[idx];
            grptot[idx] = run;
            run += v;
        }
        tot1 = run;
    }
    int pair = tot0 + tot1;
    int lane = t & 63, wv = t >> 6;
    int val = pair;
    #pragma unroll
    for (int d = 1; d < 64; d <<= 1) {
        int u = __shfl_up(val, d);
        if (lane >= d) val += u;
    }
    if (lane == 63) wsum[wv] = val;
    __syncthreads();
    if (t == 0) {
        int run = 0;
        #pragma unroll
        for (int g2 = 0; g2 < 16; g2++) { int v = wsum[g2]; wsum[g2] = run; run += v; }
    }
    __syncthreads();
    int excl = val - pair + wsum[wv];
    baseB[2 * t]     = excl;
    baseB[2 * t + 1] = excl + tot0;
    if (t == 1023) baseB[BK] = wsum[15] + __shfl(val, 63);   // total = E_
    #pragma unroll
    for (int g = 0; g < GG; g++) {
        grptot[g * BK + 2 * t]     += excl;
        grptot[g * BK + 2 * t + 1] += excl + tot0;
    }
}

// ---- A3: LDS bucket-sort 6400 edges, run-contiguous global writes.
__global__ __launch_bounds__(512)
void kA_scatter2(const int* __restrict__ row, const int* __restrict__ col,
                 const float* __restrict__ w,
                 const int* __restrict__ countsA, const int* __restrict__ countsP,
                 const int* __restrict__ grptot,
                 int2* __restrict__ brec) {
    __shared__ int  lh[BK];                 // shift
    __shared__ int  lc_[BK];                // local base -> bump cursor
    __shared__ int  wsum[8];
    __shared__ int2 srec[SCE];              // 51200 B
    __shared__ unsigned short sbid[SCE];    // 12800 B
    int c = blockIdx.x, t = threadIdx.x;
    int g = c / GCH;
    int E0 = c * SCE;
    const int4* rawp = (const int4*)(countsA + (size_t)c * BK);
    int4 hv = rawp[t];
    int tot = hv.x + hv.y + hv.z + hv.w;
    // wave-shfl scan of tot over 512 threads
    int lane = t & 63, wv = t >> 6;
    int val = tot;
    #pragma unroll
    for (int d = 1; d < 64; d <<= 1) {
        int u = __shfl_up(val, d);
        if (lane >= d) val += u;
    }
    if (lane == 63) wsum[wv] = val;
    __syncthreads();
    if (t == 0) {
        int run = 0;
        #pragma unroll
        for (int g2 = 0; g2 < 8; g2++) { int v = wsum[g2]; wsum[g2] = run; run += v; }
    }
    __syncthreads();
    int excl = val - tot + wsum[wv];
    int b0 = t * 4;
    lc_[b0]     = excl;
    lc_[b0 + 1] = excl + hv.x;
    lc_[b0 + 2] = excl + hv.x + hv.y;
    lc_[b0 + 3] = excl + hv.x + hv.y + hv.z;
    __syncthreads();
    const int* gO = grptot + g * BK;
    const int* gP = countsP + (size_t)c * BK;
    for (int i = t; i < BK; i += 512) lh[i] = gO[i] + gP[i] - lc_[i];
    __syncthreads();
    const int* cp = col + E0;
    const int* rp = row + E0;
    const float* wp = w + E0;
    #pragma unroll 4
    for (int i = t; i < SCE; i += 512) {
        int v = cp[i];
        int b = v >> 6;
        int lp = atomicAdd(&lc_[b], 1);
        srec[lp] = make_int2(rp[i] | ((v & 63) << 17), __float_as_int(wp[i]));
        sbid[lp] = (unsigned short)b;
    }
    __syncthreads();
    #pragma unroll 4
    for (int j = t; j < SCE; j += 512) {
        brec[lh[sbid[j]] + j] = srec[j];
    }
}

// ---- B-sort: per-bucket counting sort brec -> srt, single global pass
//   (records parked in registers between hist and scatter). + CSR/deg/dinv/xw.
__global__ __launch_bounds__(512)
void kB_sortdeg(const int* __restrict__ baseB, const int2* __restrict__ brec,
                int2* __restrict__ srt,
                const float* __restrict__ x,
                float* __restrict__ dinv, float* __restrict__ xw,
                int* __restrict__ nodeptr) {
    __shared__ int   h[8 * 64];        // wave-private bins
    __shared__ float degw[8 * 64];
    __shared__ int   nb[65];
    int b = blockIdx.x, t = threadIdx.x;
    int wid = t >> 6;                  // 0..7
    int st = baseB[b];
    int cnt = baseB[b + 1] - st;
    h[t] = 0;
    degw[t] = 0.0f;
    __syncthreads();
    int hb = wid << 6;
    // predicated independent loads: up to 5 records/thread in registers
    bool p0 = t < cnt, p1 = t + 512 < cnt, p2 = t + 1024 < cnt,
         p3 = t + 1536 < cnt, p4 = t + 2048 < cnt;
    int2 q0 = p0 ? brec[st + t]        : make_int2(0, 0);
    int2 q1 = p1 ? brec[st + t + 512]  : make_int2(0, 0);
    int2 q2 = p2 ? brec[st + t + 1024] : make_int2(0, 0);
    int2 q3 = p3 ? brec[st + t + 1536] : make_int2(0, 0);
    int2 q4 = p4 ? brec[st + t + 2048] : make_int2(0, 0);
    if (p0) { atomicAdd(&h[hb + (q0.x >> 17)], 1); atomicAdd(&degw[hb + (q0.x >> 17)], __int_as_float(q0.y)); }
    if (p1) { atomicAdd(&h[hb + (q1.x >> 17)], 1); atomicAdd(&degw[hb + (q1.x >> 17)], __int_as_float(q1.y)); }
    if (p2) { atomicAdd(&h[hb + (q2.x >> 17)], 1); atomicAdd(&degw[hb + (q2.x >> 17)], __int_as_float(q2.y)); }
    if (p3) { atomicAdd(&h[hb + (q3.x >> 17)], 1); atomicAdd(&degw[hb + (q3.x >> 17)], __int_as_float(q3.y)); }
    if (p4) { atomicAdd(&h[hb + (q4.x >> 17)], 1); atomicAdd(&degw[hb + (q4.x >> 17)], __int_as_float(q4.y)); }
    // fallback for cnt > 2560 (statistically never: mean 2048, sd ~45)
    for (int i = t + 2560; i < cnt; i += 512) {
        int2 q = brec[st + i];
        atomicAdd(&h[hb + (q.x >> 17)], 1);
        atomicAdd(&degw[hb + (q.x >> 17)], __int_as_float(q.y));
    }
    __syncthreads();
    if (t < 64) {
        int off = 0;
        #pragma unroll
        for (int w2 = 0; w2 < 8; w2++) {
            int cc = h[(w2 << 6) + t];
            h[(w2 << 6) + t] = off;
            off += cc;
        }
        int val = off;
        #pragma unroll
        for (int d = 1; d < 64; d <<= 1) {
            int u = __shfl_up(val, d);
            if (t >= d) val += u;
        }
        nb[t] = val - off;
        if (t == 63) nb[64] = val;
    }
    __syncthreads();
    if (t < 64) {
        int e2 = nb[t];
        #pragma unroll
        for (int w2 = 0; w2 < 8; w2++) h[(w2 << 6) + t] += e2;
    }
    __syncthreads();
    // scatter from registers (no second global read)
    if (p0) { int p = atomicAdd(&h[hb + (q0.x >> 17)], 1); srt[st + p] = make_int2(q0.x & 0x1FFFF, q0.y); }
    if (p1) { int p = atomicAdd(&h[hb + (q1.x >> 17)], 1); srt[st + p] = make_int2(q1.x & 0x1FFFF, q1.y); }
    if (p2) { int p = atomicAdd(&h[hb + (q2.x >> 17)], 1); srt[st + p] = make_int2(q2.x & 0x1FFFF, q2.y); }
    if (p3) { int p = atomicAdd(&h[hb + (q3.x >> 17)], 1); srt[st + p] = make_int2(q3.x & 0x1FFFF, q3.y); }
    if (p4) { int p = atomicAdd(&h[hb + (q4.x >> 17)], 1); srt[st + p] = make_int2(q4.x & 0x1FFFF, q4.y); }
    for (int i = t + 2560; i < cnt; i += 512) {
        int2 q = brec[st + i];
        int pos = atomicAdd(&h[hb + (q.x >> 17)], 1);
        srt[st + pos] = make_int2(q.x & 0x1FFFF, q.y);
    }
    if (t < 64) {
        int n = (b << 6) + t;
        if (n < N_) {
            float d = degw[t]       + degw[64 + t]  + degw[128 + t] + degw[192 + t]
                    + degw[256 + t] + degw[320 + t] + degw[384 + t] + degw[448 + t];
            float di = rsqrtf(d + 1.0f);
            dinv[n] = di;
            nodeptr[n] = st + nb[t];
            const float4* xi = (const float4*)(x + (size_t)n * 8);
            float4 xa = xi[0], xb = xi[1];
            float4* o = (float4*)(xw + (size_t)n * 8);
            o[0] = make_float4(di * xa.x, di * xa.y, di * xa.z, di * xa.w);
            o[1] = make_float4(di * xb.x, di * xb.y, di * xb.z, di * xb.w);
        }
        if (b == NBUCK - 1 && t == 0) nodeptr[N_] = E_;
    }
}

// ---- B2: 8 threads/node register aggregation + split MLP. Zero atomics.
__global__ __launch_bounds__(512)
void kB2_node(const int* __restrict__ nodeptr, const int2* __restrict__ srec,
              const float* __restrict__ dinv,
              const float* __restrict__ xw,
              const float* __restrict__ W1,
              const float* __restrict__ b1,
              const float* __restrict__ W2,
              float* __restrict__ tv) {
    __shared__ float sW1[8 * 64];
    __shared__ float sb1[64];
    __shared__ float sW2[64];
    int t = threadIdx.x;                  // 512 threads, 64 nodes/block
    sW1[t] = W1[t];
    if (t < 64) { sb1[t] = b1[t]; sW2[t] = W2[t]; }
    __syncthreads();
    int n = blockIdx.x * 64 + (t >> 3);
    int q = t & 7;
    if (n >= N_) return;
    int st = nodeptr[n], en = nodeptr[n + 1];
    const float4* xw4 = (const float4*)xw;
    float a[8];
    if (q == 0) {
        float4 s0 = xw4[2 * n], s1 = xw4[2 * n + 1];
        a[0] = s0.x; a[1] = s0.y; a[2] = s0.z; a[3] = s0.w;
        a[4] = s1.x; a[5] = s1.y; a[6] = s1.z; a[7] = s1.w;
    } else {
        #pragma unroll
        for (int k = 0; k < 8; k++) a[k] = 0.0f;
    }
    int e = st + q;
    for (; e + 8 < en; e += 16) {         // 2 edges per iter (stride 8)
        int2 q0 = srec[e], q1 = srec[e + 8];
        float4 f0a = xw4[2 * q0.x], f0b = xw4[2 * q0.x + 1];
        float4 f1a = xw4[2 * q1.x], f1b = xw4[2 * q1.x + 1];
        float w0 = __int_as_float(q0.y), w1 = __int_as_float(q1.y);
        a[0] = fmaf(w0, f0a.x, a[0]); a[1] = fmaf(w0, f0a.y, a[1]);
        a[2] = fmaf(w0, f0a.z, a[2]); a[3] = fmaf(w0, f0a.w, a[3]);
        a[4] = fmaf(w0, f0b.x, a[4]); a[5] = fmaf(w0, f0b.y, a[5]);
        a[6] = fmaf(w0, f0b.z, a[6]); a[7] = fmaf(w0, f0b.w, a[7]);
        a[0] = fmaf(w1, f1a.x, a[0]); a[1] = fmaf(w1, f1a.y, a[1]);
        a[2] = fmaf(w1, f1a.z, a[2]); a[3] = fmaf(w1, f1a.w, a[3]);
        a[4] = fmaf(w1, f1b.x, a[4]); a[5] = fmaf(w1, f1b.y, a[5]);
        a[6] = fmaf(w1, f1b.z, a[6]); a[7] = fmaf(w1, f1b.w, a[7]);
    }
    if (e < en) {
        int2 qq = srec[e];
        float4 fa = xw4[2 * qq.x], fb = xw4[2 * qq.x + 1];
        float w0 = __int_as_float(qq.y);
        a[0] = fmaf(w0, fa.x, a[0]); a[1] = fmaf(w0, fa.y, a[1]);
        a[2] = fmaf(w0, fa.z, a[2]); a[3] = fmaf(w0, fa.w, a[3]);
        a[4] = fmaf(w0, fb.x, a[4]); a[5] = fmaf(w0, fb.y, a[5]);
        a[6] = fmaf(w0, fb.z, a[6]); a[7] = fmaf(w0, fb.w, a[7]);
    }
    #pragma unroll
    for (int k = 0; k < 8; k++) {
        a[k] += __shfl_xor(a[k], 1);
        a[k] += __shfl_xor(a[k], 2);
        a[k] += __shfl_xor(a[k], 4);
    }
    float di = dinv[n];
    #pragma unroll
    for (int k = 0; k < 8; k++) a[k] *= di;
    float sv = 0.0f;
    int jb = q << 3;
    #pragma unroll
    for (int j = 0; j < 8; j++) {
        int jj = jb + j;
        float h = sb1[jj];
        #pragma unroll
        for (int k = 0; k < 8; k++) h = fmaf(a[k], sW1[k * 64 + jj], h);
        sv = fmaf(fmaxf(h, 0.0f), sW2[jj], sv);
    }
    sv += __shfl_xor(sv, 1);
    sv += __shfl_xor(sv, 2);
    sv += __shfl_xor(sv, 4);
    if (q == 0) tv[n] = di * sv;
}

// ---- B3: 8 threads/node layer-2.
__global__ __launch_bounds__(512)
void kB3_node(const int* __restrict__ nodeptr, const int2* __restrict__ srec,
              const float* __restrict__ dinv,
              const float* __restrict__ tv,
              const float* __restrict__ b2,
              float* __restrict__ out) {
    int t = threadIdx.x;                  // 512 threads, 64 nodes/block
    int n = blockIdx.x * 64 + (t >> 3);
    int q = t & 7;
    if (n >= N_) return;
    int st = nodeptr[n], en = nodeptr[n + 1];
    float acc = (q == 0) ? tv[n] : 0.0f;
    int e = st + q;
    for (; e + 8 < en; e += 16) {         // 2 edges per iter (stride 8)
        int2 q0 = srec[e], q1 = srec[e + 8];
        float t0 = tv[q0.x], t1 = tv[q1.x];
        acc = fmaf(__int_as_float(q0.y), t0, acc);
        acc = fmaf(__int_as_float(q1.y), t1, acc);
    }
    if (e < en) {
        int2 qq = srec[e];
        acc = fmaf(__int_as_float(qq.y), tv[qq.x], acc);
    }
    acc += __shfl_xor(acc, 1);
    acc += __shfl_xor(acc, 2);
    acc += __shfl_xor(acc, 4);
    if (q == 0) out[n] = b2[0] + dinv[n] * acc;
}

extern "C" void kernel_launch(void* const* d_in, const int* in_sizes, int n_in,
                              void* d_out, int out_size, void* d_ws, size_t ws_size,
                              hipStream_t stream) {
    const float* x  = (const float*)d_in[0];
    const int*   ei = (const int*)d_in[1];    // [2, E] int32
    const float* w  = (const float*)d_in[2];
    const float* W1 = (const float*)d_in[3];
    const float* b1 = (const float*)d_in[4];
    const float* W2 = (const float*)d_in[5];
    const float* b2 = (const float*)d_in[6];
    float* out = (float*)d_out;

    const int* row = ei;
    const int* col = ei + E_;

    // ws (ints): countsA[1024000] | countsP[1024000] | grptot[20480] |
    //   baseB[2049 pad 2560] | nodeptr[100352] | dinv[N] | xw[8N] | tv[N] |
    //   brec[E] int2 | srt[E] int2                         ~64 MB
    int*   wsI     = (int*)d_ws;
    int*   countsA = wsI;
    int*   countsP = wsI + (size_t)CA * BK;          // 1024000
    int*   grptot  = countsP + (size_t)CA * BK;      // +1024000
    int*   baseB   = grptot + GG * BK;               // +20480
    int*   nodeptr = baseB + 2560;
    float* dinv    = (float*)(nodeptr + 100352);
    float* xw      = dinv + N_;
    float* tv      = xw + (size_t)8 * N_;
    int2*  brec    = (int2*)(tv + N_);
    int2*  srt     = brec + E_;

    kA_hist    <<<CA, 512, 0, stream>>>(col, countsA);
    kA_scan1   <<<(GG * BK + 255) / 256, 256, 0, stream>>>(countsA, countsP, grptot);
    kA_scan2B  <<<1, 1024, 0, stream>>>(grptot, baseB);
    kA_scatter2<<<CA, 512, 0, stream>>>(row, col, w, countsA, countsP, grptot, brec);
    kB_sortdeg <<<NBUCK, 512, 0, stream>>>(baseB, brec, srt, x, dinv, xw, nodeptr);
    kB2_node   <<<NBUCK, 512, 0, stream>>>(nodeptr, srt, dinv, xw, W1, b1, W2, tv);
    kB3_node   <<<NBUCK, 512, 0, stream>>>(nodeptr, srt, dinv, tv, b2, out);
}